// Round 6
// baseline (484.255 us; speedup 1.0000x reference)
//
#include <hip/hip_runtime.h>
#include <hip/hip_bf16.h>

// ---------------------------------------------------------------------------
// PointCloudExtractor: T-Net -> transform -> multi-radius topK gather -> MLP
// B=8 N=2048 K=64 TU=256 U=512, blocks 512->512, 512->256, 256->170
// Pipeline (6 dispatches): memset(out), convw_t, tnet1, tnet2, topk, chain
// ---------------------------------------------------------------------------

#define BN_SCALE 0.99950037468777f   // float32(1/sqrt(1+1e-3))

typedef short short8 __attribute__((ext_vector_type(8)));
typedef float floatx4 __attribute__((ext_vector_type(4)));

// workspace layout (bytes)
#define OFF_FEATS 0                      // bf16 [16384,576]   18,874,368
#define OFF_W     18874368
#define OFF_C1WT  (OFF_W)                // bf16 [512][576]
#define OFF_RWT   (OFF_C1WT + 589824)    // bf16 [512][512]
#define OFF_B1WT  (OFF_RWT + 524288)     // bf16 [512][512]
#define OFF_B2WT  (OFF_B1WT + 524288)    // bf16 [256][512]
#define OFF_B3WT  (OFF_B2WT + 262144)    // bf16 [256][256] (rows>=170 zero)
#define OFF_PTS   (OFF_B3WT + 131072)    // f32 [8,2048,3]
#define OFF_PART  (OFF_PTS + 196608)     // f32 [8][8][256] tnet1 partial max

__device__ inline short f2bf(float x) {
    __hip_bfloat16 h = __float2bfloat16(x);
    return *reinterpret_cast<short*>(&h);
}
__device__ inline float bf2f(short s) {
    return __uint_as_float(((unsigned)(unsigned short)s) << 16);
}

// ---- coalesced tiled transpose + f32->bf16: dst[Npad][K] <- src[K][N] ------
__global__ __launch_bounds__(256)
void convw_t_k(const float* __restrict__ c1w, const float* __restrict__ rw,
               const float* __restrict__ b1w, const float* __restrict__ b2w,
               const float* __restrict__ b3w,
               short* __restrict__ c1wT, short* __restrict__ rwT,
               short* __restrict__ b1wT, short* __restrict__ b2wT,
               short* __restrict__ b3wT) {
    __shared__ float tile[64][65];
    int bid = blockIdx.x;
    const float* src; short* dst; int K, N, t;
    if (bid < 72)       { src = c1w; dst = c1wT; K = 576; N = 512; t = bid; }
    else if (bid < 136) { src = rw;  dst = rwT;  K = 512; N = 512; t = bid - 72; }
    else if (bid < 200) { src = b1w; dst = b1wT; K = 512; N = 512; t = bid - 136; }
    else if (bid < 232) { src = b2w; dst = b2wT; K = 512; N = 256; t = bid - 200; }
    else                { src = b3w; dst = b3wT; K = 256; N = 170; t = bid - 232; }
    int ktiles = K >> 6;
    int k0 = (t % ktiles) * 64, n0 = (t / ktiles) * 64;
    int tx = threadIdx.x & 63, ty = threadIdx.x >> 6;
#pragma unroll
    for (int p = 0; p < 16; p++) {
        int r = p * 4 + ty;
        int n = n0 + tx;
        tile[r][tx] = (n < N) ? src[(size_t)(k0 + r) * N + n] : 0.f;
    }
    __syncthreads();
#pragma unroll
    for (int p = 0; p < 16; p++) {
        int r = p * 4 + ty;
        dst[(size_t)(n0 + r) * K + k0 + tx] = f2bf(tile[tx][r]);
    }
}

// ---- T-Net layer 1 + partial max pool --------------------------------------
__global__ __launch_bounds__(256)
void tnet1_k(const float* __restrict__ points, const float* __restrict__ tw,
             const float* __restrict__ tb, const float* __restrict__ tg1,
             const float* __restrict__ tbt1, float* __restrict__ part) {
    __shared__ float spts[768];
    const int b = blockIdx.y;
    const int u = threadIdx.x;
    const float* pb = points + ((size_t)b * 2048 + blockIdx.x * 256) * 3;
    for (int i = u; i < 768; i += 256) spts[i] = pb[i];
    const float w0 = tw[u], w1 = tw[256 + u], w2 = tw[512 + u];
    const float bi = tb[u];
    const float gs = tg1[u] * BN_SCALE, bt = tbt1[u];
    __syncthreads();
    float m = 0.f;  // relu outputs >= 0
    for (int nn = 0; nn < 256; nn++) {
        float v = spts[nn * 3] * w0 + spts[nn * 3 + 1] * w1 +
                  spts[nn * 3 + 2] * w2 + bi;
        v = fmaxf(v * gs + bt, 0.f);
        m = fmaxf(m, v);
    }
    part[((b * 8 + blockIdx.x) << 8) + u] = m;
}

// ---- T-Net dense layers + transform pts (latency-parallel matvecs) ---------
__global__ __launch_bounds__(1024)
void tnet2_k(const float* __restrict__ points, const float* __restrict__ part,
             const float* __restrict__ td1w, const float* __restrict__ td1b,
             const float* __restrict__ tg2, const float* __restrict__ tbt2,
             const float* __restrict__ td2w, const float* __restrict__ td2b,
             float* __restrict__ pts_out) {
    __shared__ float sx[256], sp[4][256], sx2[256], sp2[9][32], sT[9];
    const int b = blockIdx.x;
    const int tid = threadIdx.x;
    if (tid < 256) {
        float m = 0.f;
#pragma unroll
        for (int c = 0; c < 8; c++) m = fmaxf(m, part[((b * 8 + c) << 8) + tid]);
        sx[tid] = m;
    }
    __syncthreads();
    {   // dense1: 256x256, v split 4 ways, unroll 8 (8 loads in flight)
        int t = tid & 255, g = tid >> 8;
        float s = 0.f;
#pragma unroll 8
        for (int i = 0; i < 64; i++) {
            int v = g * 64 + i;
            s += sx[v] * td1w[v * 256 + t];
        }
        sp[g][t] = s;
    }
    __syncthreads();
    if (tid < 256) {
        float s = td1b[tid] + sp[0][tid] + sp[1][tid] + sp[2][tid] + sp[3][tid];
        sx2[tid] = fmaxf(s * (tg2[tid] * BN_SCALE) + tbt2[tid], 0.f);
    }
    __syncthreads();
    if (tid < 288) {   // dense2: 256->9, v split 32 ways
        int j = tid / 32, vg = tid & 31;
        float s = 0.f;
#pragma unroll
        for (int i = 0; i < 8; i++) {
            int v = vg * 8 + i;
            s += sx2[v] * td2w[v * 9 + j];
        }
        sp2[j][vg] = s;
    }
    __syncthreads();
    if (tid < 9) {
        float s = td2b[tid];
        for (int vg = 0; vg < 32; vg++) s += sp2[tid][vg];
        sT[tid] = s;
    }
    __syncthreads();
    for (int n = tid; n < 2048; n += 1024) {
        size_t idx = ((size_t)b * 2048 + n) * 3;
        float p0 = points[idx], p1 = points[idx + 1], p2 = points[idx + 2];
        pts_out[idx]     = p0 * sT[0] + p1 * sT[3] + p2 * sT[6];
        pts_out[idx + 1] = p0 * sT[1] + p1 * sT[4] + p2 * sT[7];
        pts_out[idx + 2] = p0 * sT[2] + p1 * sT[5] + p2 * sT[8];
    }
}

// ---- top-K ball query + gather -> feats bf16 (unchanged from R4) -----------
__device__ inline void ins_one(unsigned& llo, unsigned& lhi, unsigned vlo,
                               unsigned vhi, int upaddr, int lane) {
    unsigned long long lv = ((unsigned long long)lhi << 32) | llo;
    unsigned long long vv = ((unsigned long long)vhi << 32) | vlo;
    unsigned long long ltm = __ballot(lv < vv);
    if (ltm) {
        int p = __builtin_ctzll(ltm);
        unsigned uplo = (unsigned)__builtin_amdgcn_ds_bpermute(upaddr, (int)llo);
        unsigned uphi = (unsigned)__builtin_amdgcn_ds_bpermute(upaddr, (int)lhi);
        if (lane >= p) {
            llo = (lane == p) ? vlo : uplo;
            lhi = (lane == p) ? vhi : uphi;
        }
    }
}

__device__ inline void run_q(unsigned& llo, unsigned& lhi, unsigned long long& th,
                             unsigned klo, unsigned khi, unsigned long long qual,
                             int upaddr, int lane) {
    do {
        int src = __builtin_ctzll(qual);
        qual &= qual - 1;
        unsigned vlo = (unsigned)__builtin_amdgcn_readlane((int)klo, src);
        unsigned vhi = (unsigned)__builtin_amdgcn_readlane((int)khi, src);
        ins_one(llo, lhi, vlo, vhi, upaddr, lane);
    } while (qual);
    th = ((unsigned long long)(unsigned)__builtin_amdgcn_readlane((int)lhi, 63) << 32)
         | (unsigned)__builtin_amdgcn_readlane((int)llo, 63);
}

__device__ inline void init_radius(bool in, unsigned nb, unsigned klo, int lane,
                                   int upaddr, unsigned& llo, unsigned& lhi,
                                   unsigned long long& th) {
    unsigned long long inm = __ballot(in);
    int S = 64 - __builtin_popcountll(inm);
    int mbI = __builtin_amdgcn_mbcnt_hi((unsigned)(inm >> 32),
              __builtin_amdgcn_mbcnt_lo((unsigned)inm, 0));
    int mbS = lane - mbI;
    int dst = in ? (S + mbI) : mbS;
    llo = (unsigned)__builtin_amdgcn_ds_permute(dst << 2, in ? 0 : (int)klo);
    lhi = 0;
    if (inm) {
        do {
            int src = __builtin_ctzll(inm);
            inm &= inm - 1;
            unsigned vlo = (unsigned)__builtin_amdgcn_readlane((int)klo, src);
            unsigned vhi = (unsigned)__builtin_amdgcn_readlane((int)nb, src);
            ins_one(llo, lhi, vlo, vhi, upaddr, lane);
        } while (inm);
    }
    th = ((unsigned long long)(unsigned)__builtin_amdgcn_readlane((int)lhi, 63) << 32)
         | (unsigned)__builtin_amdgcn_readlane((int)llo, 63);
}

__global__ __launch_bounds__(1024)
void topk_feats_k(const float* __restrict__ pts, const float* __restrict__ noise,
                  short* __restrict__ feats) {
    __shared__ float sxp[2048], syp[2048], szp[2048];
    const int b = blockIdx.y;
    const int tid = threadIdx.x;
    const int lane = tid & 63;
    const int wave = tid >> 6;
    const int n = blockIdx.x * 16 + wave;
    const float* nrow = noise + ((size_t)b * 2048 + n) * 2048;
    float ncur = nrow[lane];
    float nnxt = nrow[64 + lane];
    for (int i = tid; i < 2048; i += 1024) {
        size_t p = ((size_t)b * 2048 + i) * 3;
        sxp[i] = pts[p];
        syp[i] = pts[p + 1];
        szp[i] = pts[p + 2];
    }
    __syncthreads();
    const float qx = sxp[n], qy = syp[n], qz = szp[n];
    const int upaddr = (lane - 1) << 2;

    unsigned L0lo, L0hi, L1lo, L1hi, L2lo, L2hi;
    unsigned long long th0, th1, th2;
    {
        float dx = qx - sxp[lane], dy = qy - syp[lane], dz = qz - szp[lane];
        float d = sqrtf(dx * dx + dy * dy + dz * dz);
        unsigned nb = __float_as_uint(ncur);
        unsigned klo = 2047 - lane;
        init_radius(d <= 0.1f, nb, klo, lane, upaddr, L0lo, L0hi, th0);
        init_radius(d <= 0.3f, nb, klo, lane, upaddr, L1lo, L1hi, th1);
        init_radius(d <= 0.7f, nb, klo, lane, upaddr, L2lo, L2hi, th2);
    }
    for (int base = 64; base < 2048; base += 64) {
        float cur = nnxt;
        if (base + 64 < 2048) nnxt = nrow[base + 64 + lane];
        const int j = base + lane;
        float dx = qx - sxp[j], dy = qy - syp[j], dz = qz - szp[j];
        float d = sqrtf(dx * dx + dy * dy + dz * dz);
        unsigned nb = __float_as_uint(cur);
        unsigned klo = 2047 - j;
        unsigned k0hi = (d <= 0.1f) ? nb : 0u;
        unsigned k1hi = (d <= 0.3f) ? nb : 0u;
        unsigned k2hi = (d <= 0.7f) ? nb : 0u;
        unsigned long long key0 = ((unsigned long long)k0hi << 32) | klo;
        unsigned long long key1 = ((unsigned long long)k1hi << 32) | klo;
        unsigned long long key2 = ((unsigned long long)k2hi << 32) | klo;
        unsigned long long q0 = __ballot(key0 > th0);
        unsigned long long q1 = __ballot(key1 > th1);
        unsigned long long q2 = __ballot(key2 > th2);
        if (q0) run_q(L0lo, L0hi, th0, klo, k0hi, q0, upaddr, lane);
        if (q1) run_q(L1lo, L1hi, th1, klo, k1hi, q1, upaddr, lane);
        if (q2) run_q(L2lo, L2hi, th2, klo, k2hi, q2, upaddr, lane);
    }
    size_t basef = ((size_t)b * 2048 + n) * 576 + (size_t)lane * 9;
    int j0 = 2047 - (int)(L0lo & 0x7FFu);
    int j1 = 2047 - (int)(L1lo & 0x7FFu);
    int j2 = 2047 - (int)(L2lo & 0x7FFu);
    feats[basef + 0] = f2bf(sxp[j0]);
    feats[basef + 1] = f2bf(syp[j0]);
    feats[basef + 2] = f2bf(szp[j0]);
    feats[basef + 3] = f2bf(sxp[j1]);
    feats[basef + 4] = f2bf(syp[j1]);
    feats[basef + 5] = f2bf(szp[j1]);
    feats[basef + 6] = f2bf(sxp[j2]);
    feats[basef + 7] = f2bf(syp[j2]);
    feats[basef + 8] = f2bf(szp[j2]);
}

// ---- fused MLP chain: c1 -> residual -> b1 -> b2 -> b3 -> max --------------
// 512 blocks x 32-row stripes, 256 threads (4 waves), 32KB LDS ->
// >=2 blocks/CU co-resident (barrier overlap). Activations in XOR-swizzled
// LDS: act[r][c] at r*512 + ((c>>3 ^ (r&7))*8) + (c&7). Weights BT [Nout][K]
// bf16 straight from global/L2 with depth-2 register prefetch.

__device__ inline int act_addr(int r, int c) {
    return r * 512 + ((((c >> 3) ^ (r & 7)) << 3) | (c & 7));
}

template <int K, int JT>
__device__ inline void mm_lds(const short* __restrict__ act,
                              const short* __restrict__ BT, int colbase,
                              int lr, int lq, floatx4 (&acc)[2][JT]) {
    constexpr int KST = K / 32;
    const short* Bb = BT + (size_t)(colbase + lr) * K + lq * 8;
    short8 bf[JT], bfn[JT];
#pragma unroll
    for (int j = 0; j < JT; j++) bf[j] = *(const short8*)(Bb + j * 16 * K);
#pragma unroll
    for (int ks = 0; ks < KST; ks++) {
        if (ks + 1 < KST) {
#pragma unroll
            for (int j = 0; j < JT; j++)
                bfn[j] = *(const short8*)(Bb + j * 16 * K + (ks + 1) * 32);
        }
        short8 af[2];
        int g = ks * 4 + lq;
#pragma unroll
        for (int i = 0; i < 2; i++)
            af[i] = *(const short8*)(act + (i * 16 + lr) * 512 +
                                     ((g ^ (lr & 7)) << 3));
#pragma unroll
        for (int i = 0; i < 2; i++)
#pragma unroll
            for (int j = 0; j < JT; j++)
                acc[i][j] = __builtin_amdgcn_mfma_f32_16x16x32_bf16(af[i], bf[j],
                                                                    acc[i][j], 0, 0, 0);
#pragma unroll
        for (int j = 0; j < JT; j++) bf[j] = bfn[j];
    }
}

template <int JT, bool RELU, bool RESID>
__device__ inline void epi_store(short* __restrict__ act, floatx4 (&acc)[2][JT],
                                 int colbase, int lr, int lq,
                                 const float* __restrict__ bias,
                                 const float* __restrict__ gamma,
                                 const float* __restrict__ beta) {
    short st[2][JT][4];
#pragma unroll
    for (int j = 0; j < JT; j++) {
        int c = colbase + j * 16 + lr;
        float bi = bias[c];
        float gs = RELU ? gamma[c] * BN_SCALE : 0.f;
        float bt = RELU ? beta[c] : 0.f;
#pragma unroll
        for (int i = 0; i < 2; i++)
#pragma unroll
            for (int reg = 0; reg < 4; reg++) {
                int r = i * 16 + lq * 4 + reg;
                float v = acc[i][j][reg] + bi;
                if (RESID) v += bf2f(act[act_addr(r, c)]);
                if (RELU) v = fmaxf(v * gs + bt, 0.f);
                st[i][j][reg] = f2bf(v);
            }
    }
    __syncthreads();   // all waves done reading this layer's input
#pragma unroll
    for (int j = 0; j < JT; j++) {
        int c = colbase + j * 16 + lr;
#pragma unroll
        for (int i = 0; i < 2; i++)
#pragma unroll
            for (int reg = 0; reg < 4; reg++) {
                int r = i * 16 + lq * 4 + reg;
                act[act_addr(r, c)] = st[i][j][reg];
            }
    }
    __syncthreads();   // writes visible before next layer reads
}

__global__ __launch_bounds__(256)
void chain_k(const short* __restrict__ feats,
             const short* __restrict__ c1wT, const short* __restrict__ rwT,
             const short* __restrict__ b1wT, const short* __restrict__ b2wT,
             const short* __restrict__ b3wT,
             const float* __restrict__ c1b, const float* __restrict__ g1,
             const float* __restrict__ be1, const float* __restrict__ rb,
             const float* __restrict__ b1b, const float* __restrict__ b1g,
             const float* __restrict__ b1be,
             const float* __restrict__ b2b, const float* __restrict__ b2g,
             const float* __restrict__ b2be,
             const float* __restrict__ b3b, const float* __restrict__ b3g,
             const float* __restrict__ b3be,
             float* __restrict__ out) {
    __shared__ short act[32 * 512];   // 32 KB
    const int tid = threadIdx.x;
    const int lane = tid & 63, wq = tid >> 6;   // 4 waves
    const int lr = lane & 15, lq = lane >> 4;
    const long m0 = (long)blockIdx.x * 32;

    // ---- c1: feats[32x576] @ c1wT -> act (bn+relu). A and B from global.
    {
        floatx4 acc[2][8] = {};
        const short* Ab = feats + (m0 + lr) * 576 + lq * 8;
        const short* Bb = c1wT + (size_t)(wq * 128 + lr) * 576 + lq * 8;
        short8 bf[8], bfn[8], af[2], afn[2];
#pragma unroll
        for (int j = 0; j < 8; j++) bf[j] = *(const short8*)(Bb + j * 16 * 576);
#pragma unroll
        for (int i = 0; i < 2; i++) af[i] = *(const short8*)(Ab + i * 16 * 576);
#pragma unroll
        for (int ks = 0; ks < 18; ks++) {
            if (ks + 1 < 18) {
#pragma unroll
                for (int j = 0; j < 8; j++)
                    bfn[j] = *(const short8*)(Bb + j * 16 * 576 + (ks + 1) * 32);
#pragma unroll
                for (int i = 0; i < 2; i++)
                    afn[i] = *(const short8*)(Ab + i * 16 * 576 + (ks + 1) * 32);
            }
#pragma unroll
            for (int i = 0; i < 2; i++)
#pragma unroll
                for (int j = 0; j < 8; j++)
                    acc[i][j] = __builtin_amdgcn_mfma_f32_16x16x32_bf16(
                        af[i], bf[j], acc[i][j], 0, 0, 0);
#pragma unroll
            for (int j = 0; j < 8; j++) bf[j] = bfn[j];
#pragma unroll
            for (int i = 0; i < 2; i++) af[i] = afn[i];
        }
        epi_store<8, true, false>(act, acc, wq * 128, lr, lq, c1b, g1, be1);
    }
    // ---- residual: act = act + act@rw + rb (no relu)
    {
        floatx4 acc[2][8] = {};
        mm_lds<512, 8>(act, rwT, wq * 128, lr, lq, acc);
        epi_store<8, false, true>(act, acc, wq * 128, lr, lq, rb, nullptr, nullptr);
    }
    // ---- b1: 512 -> 512 (bn+relu)
    {
        floatx4 acc[2][8] = {};
        mm_lds<512, 8>(act, b1wT, wq * 128, lr, lq, acc);
        epi_store<8, true, false>(act, acc, wq * 128, lr, lq, b1b, b1g, b1be);
    }
    // ---- b2: 512 -> 256 (bn+relu)
    {
        floatx4 acc[2][4] = {};
        mm_lds<512, 4>(act, b2wT, wq * 64, lr, lq, acc);
        epi_store<4, true, false>(act, acc, wq * 64, lr, lq, b2b, b2g, b2be);
    }
    // ---- b3: 256 -> 170(pad 256), bn+relu, col-max over 32 rows, atomicMax
    {
        floatx4 acc[2][4] = {};
        mm_lds<256, 4>(act, b3wT, wq * 64, lr, lq, acc);
        const int bb = blockIdx.x >> 6;   // 64 blocks of 32 rows per batch
#pragma unroll
        for (int j = 0; j < 4; j++) {
            int c = wq * 64 + j * 16 + lr;
            bool valid = (c < 170);
            float bi = valid ? b3b[c] : 0.f;
            float gs = valid ? b3g[c] * BN_SCALE : 0.f;
            float bt = valid ? b3be[c] : 0.f;
            float cm = 0.f;
#pragma unroll
            for (int i = 0; i < 2; i++)
#pragma unroll
                for (int reg = 0; reg < 4; reg++) {
                    float v = fmaxf((acc[i][j][reg] + bi) * gs + bt, 0.f);
                    cm = fmaxf(cm, v);
                }
            cm = fmaxf(cm, __shfl_xor(cm, 16));
            cm = fmaxf(cm, __shfl_xor(cm, 32));
            if (lq == 0 && valid)
                atomicMax((unsigned int*)&out[bb * 170 + c], __float_as_uint(cm));
        }
    }
}

extern "C" void kernel_launch(void* const* d_in, const int* in_sizes, int n_in,
                              void* d_out, int out_size, void* d_ws, size_t ws_size,
                              hipStream_t stream) {
    const float* points = (const float*)d_in[0];
    const float* noise  = (const float*)d_in[1];
    const float* tw   = (const float*)d_in[2];
    const float* tb   = (const float*)d_in[3];
    const float* tg1  = (const float*)d_in[4];
    const float* tbt1 = (const float*)d_in[5];
    const float* td1w = (const float*)d_in[6];
    const float* td1b = (const float*)d_in[7];
    const float* tg2  = (const float*)d_in[8];
    const float* tbt2 = (const float*)d_in[9];
    const float* td2w = (const float*)d_in[10];
    const float* td2b = (const float*)d_in[11];
    const float* c1w  = (const float*)d_in[12];
    const float* c1b  = (const float*)d_in[13];
    const float* g1   = (const float*)d_in[14];
    const float* be1  = (const float*)d_in[15];
    const float* rw   = (const float*)d_in[16];
    const float* rb   = (const float*)d_in[17];
    const float* b1w  = (const float*)d_in[18];
    const float* b1b  = (const float*)d_in[19];
    const float* b1g  = (const float*)d_in[20];
    const float* b1be = (const float*)d_in[21];
    const float* b2w  = (const float*)d_in[22];
    const float* b2b  = (const float*)d_in[23];
    const float* b2g  = (const float*)d_in[24];
    const float* b2be = (const float*)d_in[25];
    const float* b3w  = (const float*)d_in[26];
    const float* b3b  = (const float*)d_in[27];
    const float* b3g  = (const float*)d_in[28];
    const float* b3be = (const float*)d_in[29];

    char* ws = (char*)d_ws;
    short* feats = (short*)(ws + OFF_FEATS);
    short* c1wT  = (short*)(ws + OFF_C1WT);
    short* rwT   = (short*)(ws + OFF_RWT);
    short* b1wT  = (short*)(ws + OFF_B1WT);
    short* b2wT  = (short*)(ws + OFF_B2WT);
    short* b3wT  = (short*)(ws + OFF_B3WT);
    float* pts   = (float*)(ws + OFF_PTS);
    float* part  = (float*)(ws + OFF_PART);

    hipMemsetAsync(d_out, 0, (size_t)out_size * sizeof(float), stream);

    convw_t_k<<<248, 256, 0, stream>>>(c1w, rw, b1w, b2w, b3w,
                                       c1wT, rwT, b1wT, b2wT, b3wT);
    tnet1_k<<<dim3(8, 8), 256, 0, stream>>>(points, tw, tb, tg1, tbt1, part);
    tnet2_k<<<8, 1024, 0, stream>>>(points, part, td1w, td1b, tg2, tbt2,
                                    td2w, td2b, pts);
    topk_feats_k<<<dim3(128, 8), 1024, 0, stream>>>(pts, noise, feats);
    chain_k<<<512, 256, 0, stream>>>(feats, c1wT, rwT, b1wT, b2wT, b3wT,
                                     c1b, g1, be1, rb, b1b, b1g, b1be,
                                     b2b, b2g, b2be, b3b, b3g, b3be,
                                     (float*)d_out);
}

// Round 7
// 445.081 us; speedup vs baseline: 1.0880x; 1.0880x over previous
//
#include <hip/hip_runtime.h>
#include <hip/hip_bf16.h>

// ---------------------------------------------------------------------------
// PointCloudExtractor: T-Net -> transform -> multi-radius topK gather -> MLP
// B=8 N=2048 K=64 TU=256 U=512, blocks 512->512, 512->256, 256->170
// Pipeline: memset(out), convw_t, tnet1, tnet2, topk, 5x gemm (m97-style)
// ---------------------------------------------------------------------------

#define BN_SCALE 0.99950037468777f   // float32(1/sqrt(1+1e-3))

typedef short short8 __attribute__((ext_vector_type(8)));
typedef float floatx4 __attribute__((ext_vector_type(4)));

typedef __attribute__((address_space(1))) const short gshort;
typedef __attribute__((address_space(3))) short lshort;

// workspace layout (bytes)
#define OFF_FEATS 0                      // bf16 [16384,576]  18,874,368 (region0)
#define OFF_R1    18874368               // region1 16,777,216: f1/f3 bf16 [16384,512]
#define OFF_W     (OFF_R1 + 16777216)
#define OFF_C1WT  (OFF_W)                // bf16 [512][576]
#define OFF_RWT   (OFF_C1WT + 589824)    // bf16 [512][512]
#define OFF_B1WT  (OFF_RWT + 524288)     // bf16 [512][512]
#define OFF_B2WT  (OFF_B1WT + 524288)    // bf16 [256][512]
#define OFF_B3WT  (OFF_B2WT + 262144)    // bf16 [256][256] (rows>=170 zero)
#define OFF_PTS   (OFF_B3WT + 131072)    // f32 [8,2048,3]
#define OFF_PART  (OFF_PTS + 196608)     // f32 [8][8][256] tnet1 partial max

__device__ inline short f2bf(float x) {
    __hip_bfloat16 h = __float2bfloat16(x);
    return *reinterpret_cast<short*>(&h);
}
__device__ inline float bf2f(short s) {
    return __uint_as_float(((unsigned)(unsigned short)s) << 16);
}

// ---- coalesced tiled transpose + f32->bf16: dst[Npad][K] <- src[K][N] ------
__global__ __launch_bounds__(256)
void convw_t_k(const float* __restrict__ c1w, const float* __restrict__ rw,
               const float* __restrict__ b1w, const float* __restrict__ b2w,
               const float* __restrict__ b3w,
               short* __restrict__ c1wT, short* __restrict__ rwT,
               short* __restrict__ b1wT, short* __restrict__ b2wT,
               short* __restrict__ b3wT) {
    __shared__ float tile[64][65];
    int bid = blockIdx.x;
    const float* src; short* dst; int K, N, t;
    if (bid < 72)       { src = c1w; dst = c1wT; K = 576; N = 512; t = bid; }
    else if (bid < 136) { src = rw;  dst = rwT;  K = 512; N = 512; t = bid - 72; }
    else if (bid < 200) { src = b1w; dst = b1wT; K = 512; N = 512; t = bid - 136; }
    else if (bid < 232) { src = b2w; dst = b2wT; K = 512; N = 256; t = bid - 200; }
    else                { src = b3w; dst = b3wT; K = 256; N = 170; t = bid - 232; }
    int ktiles = K >> 6;
    int k0 = (t % ktiles) * 64, n0 = (t / ktiles) * 64;
    int tx = threadIdx.x & 63, ty = threadIdx.x >> 6;
#pragma unroll
    for (int p = 0; p < 16; p++) {
        int r = p * 4 + ty;
        int n = n0 + tx;
        tile[r][tx] = (n < N) ? src[(size_t)(k0 + r) * N + n] : 0.f;
    }
    __syncthreads();
#pragma unroll
    for (int p = 0; p < 16; p++) {
        int r = p * 4 + ty;
        dst[(size_t)(n0 + r) * K + k0 + tx] = f2bf(tile[tx][r]);
    }
}

// ---- T-Net layer 1 + partial max pool --------------------------------------
__global__ __launch_bounds__(256)
void tnet1_k(const float* __restrict__ points, const float* __restrict__ tw,
             const float* __restrict__ tb, const float* __restrict__ tg1,
             const float* __restrict__ tbt1, float* __restrict__ part) {
    __shared__ float spts[768];
    const int b = blockIdx.y;
    const int u = threadIdx.x;
    const float* pb = points + ((size_t)b * 2048 + blockIdx.x * 256) * 3;
    for (int i = u; i < 768; i += 256) spts[i] = pb[i];
    const float w0 = tw[u], w1 = tw[256 + u], w2 = tw[512 + u];
    const float bi = tb[u];
    const float gs = tg1[u] * BN_SCALE, bt = tbt1[u];
    __syncthreads();
    float m = 0.f;  // relu outputs >= 0
    for (int nn = 0; nn < 256; nn++) {
        float v = spts[nn * 3] * w0 + spts[nn * 3 + 1] * w1 +
                  spts[nn * 3 + 2] * w2 + bi;
        v = fmaxf(v * gs + bt, 0.f);
        m = fmaxf(m, v);
    }
    part[((b * 8 + blockIdx.x) << 8) + u] = m;
}

// ---- T-Net dense layers + transform pts (latency-parallel matvecs) ---------
__global__ __launch_bounds__(1024)
void tnet2_k(const float* __restrict__ points, const float* __restrict__ part,
             const float* __restrict__ td1w, const float* __restrict__ td1b,
             const float* __restrict__ tg2, const float* __restrict__ tbt2,
             const float* __restrict__ td2w, const float* __restrict__ td2b,
             float* __restrict__ pts_out) {
    __shared__ float sx[256], sp[4][256], sx2[256], sp2[9][32], sT[9];
    const int b = blockIdx.x;
    const int tid = threadIdx.x;
    if (tid < 256) {
        float m = 0.f;
#pragma unroll
        for (int c = 0; c < 8; c++) m = fmaxf(m, part[((b * 8 + c) << 8) + tid]);
        sx[tid] = m;
    }
    __syncthreads();
    {   // dense1: 256x256, v split 4 ways, unroll 8 (8 loads in flight)
        int t = tid & 255, g = tid >> 8;
        float s = 0.f;
#pragma unroll 8
        for (int i = 0; i < 64; i++) {
            int v = g * 64 + i;
            s += sx[v] * td1w[v * 256 + t];
        }
        sp[g][t] = s;
    }
    __syncthreads();
    if (tid < 256) {
        float s = td1b[tid] + sp[0][tid] + sp[1][tid] + sp[2][tid] + sp[3][tid];
        sx2[tid] = fmaxf(s * (tg2[tid] * BN_SCALE) + tbt2[tid], 0.f);
    }
    __syncthreads();
    if (tid < 288) {   // dense2: 256->9, v split 32 ways
        int j = tid / 32, vg = tid & 31;
        float s = 0.f;
#pragma unroll
        for (int i = 0; i < 8; i++) {
            int v = vg * 8 + i;
            s += sx2[v] * td2w[v * 9 + j];
        }
        sp2[j][vg] = s;
    }
    __syncthreads();
    if (tid < 9) {
        float s = td2b[tid];
        for (int vg = 0; vg < 32; vg++) s += sp2[tid][vg];
        sT[tid] = s;
    }
    __syncthreads();
    for (int n = tid; n < 2048; n += 1024) {
        size_t idx = ((size_t)b * 2048 + n) * 3;
        float p0 = points[idx], p1 = points[idx + 1], p2 = points[idx + 2];
        pts_out[idx]     = p0 * sT[0] + p1 * sT[3] + p2 * sT[6];
        pts_out[idx + 1] = p0 * sT[1] + p1 * sT[4] + p2 * sT[7];
        pts_out[idx + 2] = p0 * sT[2] + p1 * sT[5] + p2 * sT[8];
    }
}

// ---- top-K ball query + gather -> feats bf16 (unchanged from R4) -----------
__device__ inline void ins_one(unsigned& llo, unsigned& lhi, unsigned vlo,
                               unsigned vhi, int upaddr, int lane) {
    unsigned long long lv = ((unsigned long long)lhi << 32) | llo;
    unsigned long long vv = ((unsigned long long)vhi << 32) | vlo;
    unsigned long long ltm = __ballot(lv < vv);
    if (ltm) {
        int p = __builtin_ctzll(ltm);
        unsigned uplo = (unsigned)__builtin_amdgcn_ds_bpermute(upaddr, (int)llo);
        unsigned uphi = (unsigned)__builtin_amdgcn_ds_bpermute(upaddr, (int)lhi);
        if (lane >= p) {
            llo = (lane == p) ? vlo : uplo;
            lhi = (lane == p) ? vhi : uphi;
        }
    }
}

__device__ inline void run_q(unsigned& llo, unsigned& lhi, unsigned long long& th,
                             unsigned klo, unsigned khi, unsigned long long qual,
                             int upaddr, int lane) {
    do {
        int src = __builtin_ctzll(qual);
        qual &= qual - 1;
        unsigned vlo = (unsigned)__builtin_amdgcn_readlane((int)klo, src);
        unsigned vhi = (unsigned)__builtin_amdgcn_readlane((int)khi, src);
        ins_one(llo, lhi, vlo, vhi, upaddr, lane);
    } while (qual);
    th = ((unsigned long long)(unsigned)__builtin_amdgcn_readlane((int)lhi, 63) << 32)
         | (unsigned)__builtin_amdgcn_readlane((int)llo, 63);
}

__device__ inline void init_radius(bool in, unsigned nb, unsigned klo, int lane,
                                   int upaddr, unsigned& llo, unsigned& lhi,
                                   unsigned long long& th) {
    unsigned long long inm = __ballot(in);
    int S = 64 - __builtin_popcountll(inm);
    int mbI = __builtin_amdgcn_mbcnt_hi((unsigned)(inm >> 32),
              __builtin_amdgcn_mbcnt_lo((unsigned)inm, 0));
    int mbS = lane - mbI;
    int dst = in ? (S + mbI) : mbS;
    llo = (unsigned)__builtin_amdgcn_ds_permute(dst << 2, in ? 0 : (int)klo);
    lhi = 0;
    if (inm) {
        do {
            int src = __builtin_ctzll(inm);
            inm &= inm - 1;
            unsigned vlo = (unsigned)__builtin_amdgcn_readlane((int)klo, src);
            unsigned vhi = (unsigned)__builtin_amdgcn_readlane((int)nb, src);
            ins_one(llo, lhi, vlo, vhi, upaddr, lane);
        } while (inm);
    }
    th = ((unsigned long long)(unsigned)__builtin_amdgcn_readlane((int)lhi, 63) << 32)
         | (unsigned)__builtin_amdgcn_readlane((int)llo, 63);
}

__global__ __launch_bounds__(1024)
void topk_feats_k(const float* __restrict__ pts, const float* __restrict__ noise,
                  short* __restrict__ feats) {
    __shared__ float sxp[2048], syp[2048], szp[2048];
    const int b = blockIdx.y;
    const int tid = threadIdx.x;
    const int lane = tid & 63;
    const int wave = tid >> 6;
    const int n = blockIdx.x * 16 + wave;
    const float* nrow = noise + ((size_t)b * 2048 + n) * 2048;
    float ncur = nrow[lane];
    float nnxt = nrow[64 + lane];
    for (int i = tid; i < 2048; i += 1024) {
        size_t p = ((size_t)b * 2048 + i) * 3;
        sxp[i] = pts[p];
        syp[i] = pts[p + 1];
        szp[i] = pts[p + 2];
    }
    __syncthreads();
    const float qx = sxp[n], qy = syp[n], qz = szp[n];
    const int upaddr = (lane - 1) << 2;

    unsigned L0lo, L0hi, L1lo, L1hi, L2lo, L2hi;
    unsigned long long th0, th1, th2;
    {
        float dx = qx - sxp[lane], dy = qy - syp[lane], dz = qz - szp[lane];
        float d = sqrtf(dx * dx + dy * dy + dz * dz);
        unsigned nb = __float_as_uint(ncur);
        unsigned klo = 2047 - lane;
        init_radius(d <= 0.1f, nb, klo, lane, upaddr, L0lo, L0hi, th0);
        init_radius(d <= 0.3f, nb, klo, lane, upaddr, L1lo, L1hi, th1);
        init_radius(d <= 0.7f, nb, klo, lane, upaddr, L2lo, L2hi, th2);
    }
    for (int base = 64; base < 2048; base += 64) {
        float cur = nnxt;
        if (base + 64 < 2048) nnxt = nrow[base + 64 + lane];
        const int j = base + lane;
        float dx = qx - sxp[j], dy = qy - syp[j], dz = qz - szp[j];
        float d = sqrtf(dx * dx + dy * dy + dz * dz);
        unsigned nb = __float_as_uint(cur);
        unsigned klo = 2047 - j;
        unsigned k0hi = (d <= 0.1f) ? nb : 0u;
        unsigned k1hi = (d <= 0.3f) ? nb : 0u;
        unsigned k2hi = (d <= 0.7f) ? nb : 0u;
        unsigned long long key0 = ((unsigned long long)k0hi << 32) | klo;
        unsigned long long key1 = ((unsigned long long)k1hi << 32) | klo;
        unsigned long long key2 = ((unsigned long long)k2hi << 32) | klo;
        unsigned long long q0 = __ballot(key0 > th0);
        unsigned long long q1 = __ballot(key1 > th1);
        unsigned long long q2 = __ballot(key2 > th2);
        if (q0) run_q(L0lo, L0hi, th0, klo, k0hi, q0, upaddr, lane);
        if (q1) run_q(L1lo, L1hi, th1, klo, k1hi, q1, upaddr, lane);
        if (q2) run_q(L2lo, L2hi, th2, klo, k2hi, q2, upaddr, lane);
    }
    size_t basef = ((size_t)b * 2048 + n) * 576 + (size_t)lane * 9;
    int j0 = 2047 - (int)(L0lo & 0x7FFu);
    int j1 = 2047 - (int)(L1lo & 0x7FFu);
    int j2 = 2047 - (int)(L2lo & 0x7FFu);
    feats[basef + 0] = f2bf(sxp[j0]);
    feats[basef + 1] = f2bf(syp[j0]);
    feats[basef + 2] = f2bf(szp[j0]);
    feats[basef + 3] = f2bf(sxp[j1]);
    feats[basef + 4] = f2bf(syp[j1]);
    feats[basef + 5] = f2bf(szp[j1]);
    feats[basef + 6] = f2bf(sxp[j2]);
    feats[basef + 7] = f2bf(syp[j2]);
    feats[basef + 8] = f2bf(szp[j2]);
}

// ---- bf16 MFMA GEMM, m97 structure: 128x128 tile, 4 waves, async staging ---
// A [M,K] bf16 row-major, BT [Npad,K] bf16. LDS unpadded [128][32] (required:
// global_load_lds writes wave-uniform base + lane*16).
// EPI 0: relu(bn(acc+bias)) -> bf16 | EPI 1: acc+bias+resid -> bf16
// EPI 2: relu(bn(acc+bias)) -> col-max over tile rows, atomicMax into out
template <int EPI>
__global__ __launch_bounds__(256)
void gemm_k(const short* __restrict__ A, const short* __restrict__ BT,
            int K, int Nact,
            const float* __restrict__ bias, const float* __restrict__ gamma,
            const float* __restrict__ beta,
            short* __restrict__ outB, float* __restrict__ outF,
            const short* __restrict__ resid) {
    __shared__ short sA[128 * 32];
    __shared__ short sB[128 * 32];
    const int tid = threadIdx.x;
    const int lane = tid & 63;
    const int wave = tid >> 6;
    const int wm = wave & 1, wn = wave >> 1;
    const int lr = lane & 15, lq = lane >> 4;
    const long m0 = (long)blockIdx.x * 128;
    const long n0 = (long)blockIdx.y * 128;

    // staging map: chunk = wave*2+c covers rows chunk*16..+15 of the tile;
    // lane L -> row chunk*16 + L/4, 16B piece (L%4) within the 64B row.
    const int srow = (lane >> 2);
    const int sp8 = (lane & 3) * 8;

    floatx4 acc[4][4];
#pragma unroll
    for (int i = 0; i < 4; i++)
#pragma unroll
        for (int j = 0; j < 4; j++) acc[i][j] = (floatx4){0.f, 0.f, 0.f, 0.f};

    for (int k0 = 0; k0 < K; k0 += 32) {
        __syncthreads();
#pragma unroll
        for (int c = 0; c < 2; c++) {
            int chunk = wave * 2 + c;
            int rr = chunk * 16 + srow;
            __builtin_amdgcn_global_load_lds(
                (gshort*)(A + (m0 + rr) * K + k0 + sp8),
                (lshort*)&sA[chunk * 512], 16, 0, 0);
            __builtin_amdgcn_global_load_lds(
                (gshort*)(BT + (n0 + rr) * K + k0 + sp8),
                (lshort*)&sB[chunk * 512], 16, 0, 0);
        }
        __syncthreads();   // drains vmcnt (global_load_lds) before use
        short8 af[4], bf[4];
#pragma unroll
        for (int i = 0; i < 4; i++)
            af[i] = *(const short8*)(&sA[(wm * 64 + i * 16 + lr) * 32 + lq * 8]);
#pragma unroll
        for (int j = 0; j < 4; j++)
            bf[j] = *(const short8*)(&sB[(wn * 64 + j * 16 + lr) * 32 + lq * 8]);
#pragma unroll
        for (int i = 0; i < 4; i++)
#pragma unroll
            for (int j = 0; j < 4; j++)
                acc[i][j] = __builtin_amdgcn_mfma_f32_16x16x32_bf16(af[i], bf[j],
                                                                    acc[i][j], 0, 0, 0);
    }

#pragma unroll
    for (int j = 0; j < 4; j++) {
        long col = n0 + wn * 64 + j * 16 + lr;
        if (col >= Nact) continue;
        float bi = bias[col];
        float gs = 0.f, bt = 0.f;
        if (EPI != 1) { gs = gamma[col] * BN_SCALE; bt = beta[col]; }
        float colmax = 0.f;
#pragma unroll
        for (int i = 0; i < 4; i++) {
#pragma unroll
            for (int rg = 0; rg < 4; rg++) {
                long row = m0 + wm * 64 + i * 16 + lq * 4 + rg;
                float v = acc[i][j][rg];
                if (EPI == 1) {
                    v = v + bi + bf2f(resid[row * Nact + col]);
                    outB[row * Nact + col] = f2bf(v);
                } else {
                    v = fmaxf((v + bi) * gs + bt, 0.f);
                    if (EPI == 0) outB[row * Nact + col] = f2bf(v);
                    else colmax = fmaxf(colmax, v);
                }
            }
        }
        if (EPI == 2) {
            // combine the 4 lq-groups (same col, different rows)
            colmax = fmaxf(colmax, __shfl_xor(colmax, 16));
            colmax = fmaxf(colmax, __shfl_xor(colmax, 32));
            if (lq == 0) {
                int bb = (int)(m0 >> 11);  // 128-row tile never crosses batch
                atomicMax((unsigned int*)&outF[bb * 170 + col],
                          __float_as_uint(colmax));
            }
        }
    }
}

extern "C" void kernel_launch(void* const* d_in, const int* in_sizes, int n_in,
                              void* d_out, int out_size, void* d_ws, size_t ws_size,
                              hipStream_t stream) {
    const float* points = (const float*)d_in[0];
    const float* noise  = (const float*)d_in[1];
    const float* tw   = (const float*)d_in[2];
    const float* tb   = (const float*)d_in[3];
    const float* tg1  = (const float*)d_in[4];
    const float* tbt1 = (const float*)d_in[5];
    const float* td1w = (const float*)d_in[6];
    const float* td1b = (const float*)d_in[7];
    const float* tg2  = (const float*)d_in[8];
    const float* tbt2 = (const float*)d_in[9];
    const float* td2w = (const float*)d_in[10];
    const float* td2b = (const float*)d_in[11];
    const float* c1w  = (const float*)d_in[12];
    const float* c1b  = (const float*)d_in[13];
    const float* g1   = (const float*)d_in[14];
    const float* be1  = (const float*)d_in[15];
    const float* rw   = (const float*)d_in[16];
    const float* rb   = (const float*)d_in[17];
    const float* b1w  = (const float*)d_in[18];
    const float* b1b  = (const float*)d_in[19];
    const float* b1g  = (const float*)d_in[20];
    const float* b1be = (const float*)d_in[21];
    const float* b2w  = (const float*)d_in[22];
    const float* b2b  = (const float*)d_in[23];
    const float* b2g  = (const float*)d_in[24];
    const float* b2be = (const float*)d_in[25];
    const float* b3w  = (const float*)d_in[26];
    const float* b3b  = (const float*)d_in[27];
    const float* b3g  = (const float*)d_in[28];
    const float* b3be = (const float*)d_in[29];

    char* ws = (char*)d_ws;
    short* feats = (short*)(ws + OFF_FEATS);   // region0
    short* f1    = (short*)(ws + OFF_R1);      // region1
    short* f2    = feats;                      // region0 reuse (feats dead)
    short* f3    = (short*)(ws + OFF_R1);      // region1 reuse (f1 dead)
    short* f4    = feats;                      // region0 reuse (f2 dead)
    short* c1wT  = (short*)(ws + OFF_C1WT);
    short* rwT   = (short*)(ws + OFF_RWT);
    short* b1wT  = (short*)(ws + OFF_B1WT);
    short* b2wT  = (short*)(ws + OFF_B2WT);
    short* b3wT  = (short*)(ws + OFF_B3WT);
    float* pts   = (float*)(ws + OFF_PTS);
    float* part  = (float*)(ws + OFF_PART);

    hipMemsetAsync(d_out, 0, (size_t)out_size * sizeof(float), stream);

    convw_t_k<<<248, 256, 0, stream>>>(c1w, rw, b1w, b2w, b3w,
                                       c1wT, rwT, b1wT, b2wT, b3wT);
    tnet1_k<<<dim3(8, 8), 256, 0, stream>>>(points, tw, tb, tg1, tbt1, part);
    tnet2_k<<<8, 1024, 0, stream>>>(points, part, td1w, td1b, tg2, tbt2,
                                    td2w, td2b, pts);
    topk_feats_k<<<dim3(128, 8), 1024, 0, stream>>>(pts, noise, feats);

    gemm_k<0><<<dim3(128, 4), 256, 0, stream>>>(feats, c1wT, 576, 512, c1b, g1, be1,
                                                f1, nullptr, nullptr);
    gemm_k<1><<<dim3(128, 4), 256, 0, stream>>>(f1, rwT, 512, 512, rb, nullptr, nullptr,
                                                f2, nullptr, f1);
    gemm_k<0><<<dim3(128, 4), 256, 0, stream>>>(f2, b1wT, 512, 512, b1b, b1g, b1be,
                                                f3, nullptr, nullptr);
    gemm_k<0><<<dim3(128, 2), 256, 0, stream>>>(f3, b2wT, 512, 256, b2b, b2g, b2be,
                                                f4, nullptr, nullptr);
    gemm_k<2><<<dim3(128, 2), 256, 0, stream>>>(f4, b3wT, 256, 170, b3b, b3g, b3be,
                                                nullptr, (float*)d_out, nullptr);
}